// Round 2
// 221.890 us; speedup vs baseline: 1.0100x; 1.0100x over previous
//
#include <hip/hip_runtime.h>

#define BATCH 32
#define NFREQ 128
#define NTIME 8192
#define NROWS (BATCH * NFREQ)   // 4096 (b,i) output rows

// ---------------------------------------------------------------------------
// Phase 1: gather the only two time-columns each output row needs and
// pre-blend them over x.
//
// TRANSPOSED mapping vs the 223.8us baseline: lane index = i (the x-gather
// coordinate), row index = (b,y). A wave's 64 lanes now read
// S[b, y, x0(0..63)] -- 64 addresses at ~258 B stride spanning ~16.5 KB of
// ONE input row (same DRAM page region), instead of the previous 64
// addresses at 32 KB stride spanning 2 MB (worst-case page/channel
// locality). Same bytes fetched, far better DRAM efficiency.
//
// W layout: W[(b*NFREQ + y)*NFREQ + i]  ==  W[tid]  -> coalesced stores.
// ---------------------------------------------------------------------------
__global__ __launch_bounds__(256) void gather_blend_kernel(
    const float* __restrict__ S,
    float* __restrict__ W)
{
    const int tid = blockIdx.x * 256 + threadIdx.x;   // 0 .. 524287
    const int i   = tid & (NFREQ - 1);                // lane-contiguous: i
    const int ry  = tid >> 7;                         // b*NFREQ + y

    const float Tm1 = (float)(NTIME - 1);
    const float Fm1 = (float)(NFREQ - 1);

    // x_pix = i/(F-1)*(T-1), border clamp (no-op for valid i, kept faithful)
    float x_pix = ((float)i / Fm1) * Tm1;
    x_pix = fminf(fmaxf(x_pix, 0.0f), Tm1);
    const int   x0 = (int)floorf(x_pix);
    const int   x1 = min(x0 + 1, NTIME - 1);
    const float wx = x_pix - (float)x0;

    const float* p = S + (size_t)ry * NTIME;          // input row (b,y)
    const float v0 = p[x0];
    const float v1 = p[x1];
    W[tid] = v0 + wx * (v1 - v0);                     // W[(b,y)][i], coalesced
}

// ---------------------------------------------------------------------------
// Phase 2: pure streaming. One block per (b,i) output row: read the 128-float
// m vector as a column of W (m[y] = W[(b,y)][i], stride-512B 4B reads --
// only 512 B of live data per block, L2/L3-resident since phase 1 just wrote
// it), then write the 32 KB output row with a per-j 1-D lerp in y.
// No global loads in the store loop.
// ---------------------------------------------------------------------------
__global__ __launch_bounds__(256) void stream_kernel(
    const float* __restrict__ W,
    const int* __restrict__ src_p,
    const int* __restrict__ dst_p,
    float* __restrict__ out)
{
    const float sourcef = (float)src_p[0];
    const float destf   = (float)dst_p[0];
    const float Tm1 = (float)(NTIME - 1);
    const float Fm1 = (float)(NFREQ - 1);
    const float inv_left  = sourcef / destf;                                   // 1/left_ratio
    const float inv_right = ((float)NTIME - sourcef) / ((float)NTIME - destf); // 1/right_ratio
    const float y_scale   = Fm1 / Tm1;

    const int row = blockIdx.x;          // b*NFREQ + i
    const int i   = row & (NFREQ - 1);
    const int b   = row >> 7;

    __shared__ float m[NFREQ];
    if (threadIdx.x < NFREQ) {
        // column i of batch-b tile of W: W[(b*128 + y)*128 + i]
        m[threadIdx.x] = W[((size_t)((b << 7) + threadIdx.x) << 7) + i];
    }
    __syncthreads();

    float* orow = out + (size_t)row * NTIME;

#pragma unroll
    for (int c = 0; c < 8; ++c) {
        const int f = c * 256 + threadIdx.x;   // float4 index within the row
        const int j0 = f * 4;
        float4 r;
        float* rp = &r.x;
#pragma unroll
        for (int k = 0; k < 4; ++k) {
            const float t = (float)(j0 + k);
            float idx = (t < destf) ? (t * inv_left)
                                    : fmaf(t - destf, inv_right, sourcef);
            idx = fminf(fmaxf(idx, 0.0f), Tm1);          // clip to [0, T-1]
            float y_pix = idx * y_scale;
            y_pix = fminf(fmaxf(y_pix, 0.0f), Fm1);      // border clamp
            const float y0f = floorf(y_pix);
            const int   y0  = (int)y0f;
            const int   y1  = min(y0 + 1, NFREQ - 1);
            const float wy  = y_pix - y0f;
            const float m0  = m[y0];
            rp[k] = m0 + wy * (m[y1] - m0);
        }
        ((float4*)orow)[f] = r;                          // coalesced 16B store
    }
}

// ---------------------------------------------------------------------------
// Fallback single-kernel path in case ws_size < 2 MB (unchanged math).
// ---------------------------------------------------------------------------
__global__ __launch_bounds__(256) void timewarp_fused_kernel(
    const float* __restrict__ S,
    const int* __restrict__ src_p,
    const int* __restrict__ dst_p,
    float* __restrict__ out)
{
    const float sourcef = (float)src_p[0];
    const float destf   = (float)dst_p[0];
    const float Tm1 = (float)(NTIME - 1);
    const float Fm1 = (float)(NFREQ - 1);
    const float inv_left  = sourcef / destf;
    const float inv_right = ((float)NTIME - sourcef) / ((float)NTIME - destf);
    const float y_scale   = Fm1 / Tm1;

    const int row = blockIdx.x;
    const int i   = row & (NFREQ - 1);
    const int b   = row >> 7;

    float x_pix = ((float)i / Fm1) * Tm1;
    x_pix = fminf(fmaxf(x_pix, 0.0f), Tm1);
    const int   x0 = (int)floorf(x_pix);
    const int   x1 = min(x0 + 1, NTIME - 1);
    const float wx = x_pix - (float)x0;

    const float* Sb = S + (size_t)b * (NFREQ * NTIME);

    __shared__ float m[NFREQ];
    if (threadIdx.x < NFREQ) {
        const int y = threadIdx.x;
        const float v0 = Sb[(size_t)y * NTIME + x0];
        const float v1 = Sb[(size_t)y * NTIME + x1];
        m[y] = v0 + wx * (v1 - v0);
    }
    __syncthreads();

    float* orow = out + (size_t)row * NTIME;
#pragma unroll
    for (int c = 0; c < 8; ++c) {
        const int f = c * 256 + threadIdx.x;
        const int j0 = f * 4;
        float4 r;
        float* rp = &r.x;
#pragma unroll
        for (int k = 0; k < 4; ++k) {
            const float t = (float)(j0 + k);
            float idx = (t < destf) ? (t * inv_left)
                                    : fmaf(t - destf, inv_right, sourcef);
            idx = fminf(fmaxf(idx, 0.0f), Tm1);
            float y_pix = idx * y_scale;
            y_pix = fminf(fmaxf(y_pix, 0.0f), Fm1);
            const float y0f = floorf(y_pix);
            const int   y0  = (int)y0f;
            const int   y1  = min(y0 + 1, NFREQ - 1);
            const float wy  = y_pix - y0f;
            const float m0  = m[y0];
            rp[k] = m0 + wy * (m[y1] - m0);
        }
        ((float4*)orow)[f] = r;
    }
}

extern "C" void kernel_launch(void* const* d_in, const int* in_sizes, int n_in,
                              void* d_out, int out_size, void* d_ws, size_t ws_size,
                              hipStream_t stream) {
    const float* S   = (const float*)d_in[0];
    const int*   sp  = (const int*)d_in[1];
    const int*   dp  = (const int*)d_in[2];
    float*       out = (float*)d_out;

    const size_t w_bytes = (size_t)NROWS * NFREQ * sizeof(float);  // 2 MB

    if (ws_size >= w_bytes) {
        float* W = (float*)d_ws;
        // Phase 1: 524288 threads, one per (ry, i); lane-contiguous in i
        gather_blend_kernel<<<dim3(NROWS * NFREQ / 256), dim3(256), 0, stream>>>(S, W);
        // Phase 2: one block per (b,i) output row
        stream_kernel<<<dim3(NROWS), dim3(256), 0, stream>>>(W, sp, dp, out);
    } else {
        timewarp_fused_kernel<<<dim3(NROWS), dim3(256), 0, stream>>>(S, sp, dp, out);
    }
}